// Round 19
// baseline (208.080 us; speedup 1.0000x reference)
//
#include <hip/hip_runtime.h>
#include <stdint.h>

typedef unsigned long long u64;
typedef float f32x4 __attribute__((ext_vector_type(4)));
typedef int   i32x4 __attribute__((ext_vector_type(4)));

// key: ((b*41+z)<<20) | y<<10 | x   (b<4, z<41, y,x<1024)
// -> 164*2^20 = 171,966,464 keys; monotone-equivalent to reference hash
// b*1025^3+z*1025^2+y*1025+x (lex order (b,z,y,x) preserved, bijective).
#define NWORDS 2686976u             // 164*2^20/64 words
#define GW 4096u                    // words per block (256 thr x 16 words)
#define NGROUPS 656u                // NWORDS/GW (exact)

__device__ __forceinline__ uint32_t pack4i(i32x4 v) {
    // v = (b, z, y, x)
    return (((uint32_t)v.x * 41u + (uint32_t)v.y) << 20) |
           ((uint32_t)v.z << 10) | (uint32_t)v.w;
}

// ---------------- phase 1: presence bits ----------------
// Fire-and-forget atomicOr only (round-6 lesson: no contended counters, no return use).
// sidx is touched exactly once -> nontemporal (keep L2/L3 for the words table).
__global__ void set_bits(const int* __restrict__ sidx, u64* __restrict__ words, int ns) {
    int i = blockIdx.x * blockDim.x + threadIdx.x;
    if (i >= ns) return;
    i32x4 v = __builtin_nontemporal_load((const i32x4*)sidx + i);
    uint32_t k = pack4i(v);
    atomicOr(&words[k >> 6], 1ull << (k & 63u));
}

// ---------------- phase 2: per-group bit counts (wave-coalesced streaming reads) ----------------
__global__ void group_popcount(const u64* __restrict__ words, uint32_t* __restrict__ groupSum) {
    __shared__ uint32_t s[256];
    uint32_t t = 0;
    size_t base = (size_t)blockIdx.x * GW;
    #pragma unroll
    for (int j = 0; j < 16; ++j)
        t += (uint32_t)__popcll(words[base + j * 256u + threadIdx.x]);
    s[threadIdx.x] = t;
    __syncthreads();
    #pragma unroll
    for (int off = 128; off > 0; off >>= 1) {
        if (threadIdx.x < (unsigned)off) s[threadIdx.x] += s[threadIdx.x + off];
        __syncthreads();
    }
    if (threadIdx.x == 0) groupSum[blockIdx.x] = s[0];
}

// ---------------- phase 3: per-word prefix + sorted decoded indice ----------------
// groupSum entries are FINALIZED by the kernel boundary (round-10 lesson: no
// intra-kernel cross-XCD producer-consumer spin). prefixArr writes are dense
// coalesced lines; outI is write-once -> nontemporal stores.
__global__ void word_prefix_indice(const u64* __restrict__ words,
                                   const uint32_t* __restrict__ groupSum,
                                   uint32_t* __restrict__ prefixArr,
                                   float* __restrict__ outI) {
    __shared__ uint32_t s[256];
    __shared__ uint32_t baseSh;
    const int tid = threadIdx.x, bid = blockIdx.x;
    size_t w0 = (size_t)bid * GW + (size_t)tid * 16;
    u64 w[16];
    uint32_t tsum = 0;
    #pragma unroll
    for (int j = 0; j < 16; ++j) { w[j] = words[w0 + j]; tsum += (uint32_t)__popcll(w[j]); }
    s[tid] = tsum;
    __syncthreads();
    #pragma unroll
    for (int off = 1; off < 256; off <<= 1) {
        uint32_t u = (tid >= off) ? s[tid - off] : 0u;
        __syncthreads();
        s[tid] += u;
        __syncthreads();
    }
    uint32_t exclInBlock = s[tid] - tsum;
    // wave 0: sum of preceding blocks' totals (empty loop for bid==0 -> 0)
    if (tid < 64) {
        uint32_t sum = 0;
        for (int g = tid; g < bid; g += 64) sum += groupSum[g];
        #pragma unroll
        for (int off = 32; off > 0; off >>= 1) sum += __shfl_down(sum, off);
        if (tid == 0) baseSh = sum;
    }
    __syncthreads();
    uint32_t run = baseSh + exclInBlock;   // exclusive rank at this thread's first word
    #pragma unroll
    for (int j = 0; j < 16; ++j) {
        prefixArr[w0 + j] = run;
        u64 word = w[j];
        uint32_t kw = (uint32_t)(w0 + j) << 6;
        while (word) {
            int b = (int)__builtin_ctzll(word);
            word &= word - 1;
            uint32_t k = kw | (uint32_t)b;
            uint32_t bz = k >> 20;
            f32x4 rec = { (float)(bz / 41u), (float)(bz % 41u),
                          (float)((k >> 10) & 1023u), (float)(k & 1023u) };
            __builtin_nontemporal_store(rec, (f32x4*)outI + run);
            ++run;
        }
    }
}

// ---------------- phase 4: fused teacher pass — compact claims, then move cooperatively ----
// Phase A (per-thread): probe (2 independent random loads) + claim atomic; winners
// record (t,p) into an LDS compaction buffer (LDS = trivially coherent; rounds 15-17
// showed cross-kernel scattered 4B winner hand-off loses claims — keep it in-block).
// Losers (~46K of 2M) append to the global overflow list (8B entries; validated
// absmax-0 across rounds 11-14, 18).
// Phase B (per-wave): move claimed rows 8-per-wave-issue, 16B/lane, 100% lane-active.
// ALL single-touch traffic (tidx, tfeat, feat) is nontemporal so the 2M random
// probes keep words+prefixArr (32MB = aggregate L2) resident.
__global__ void teacher_fused(const int* __restrict__ tidx, const float* __restrict__ tfeat,
                              const u64* __restrict__ words, const uint32_t* __restrict__ prefixArr,
                              uint32_t* __restrict__ cnt,
                              uint2* __restrict__ ovf, uint32_t* __restrict__ ovfCount,
                              float* __restrict__ feat, int nt) {
    __shared__ uint32_t sT[256];
    __shared__ uint32_t sP[256];
    __shared__ uint32_t sCount;
    const int tid = threadIdx.x;
    int t = blockIdx.x * 256 + tid;

    if (tid == 0) sCount = 0u;
    __syncthreads();

    if (t < nt) {
        i32x4 c = __builtin_nontemporal_load((const i32x4*)tidx + t);
        uint32_t k = pack4i(c);
        u64 word = words[k >> 6];                 // independent random loads (keep cached)
        uint32_t pfx = prefixArr[k >> 6];
        u64 bit = 1ull << (k & 63u);
        if (word & bit) {
            uint32_t p = pfx + (uint32_t)__popcll(word & (bit - 1ull));
            uint32_t old = atomicAdd(&cnt[p], 1u);
            if (old == 0u) {
                uint32_t i = atomicAdd(&sCount, 1u);   // LDS atomic: cheap
                sT[i] = (uint32_t)t;
                sP[i] = p;
            } else {
                uint32_t idx = atomicAdd(ovfCount, 1u);
                ovf[idx] = make_uint2((uint32_t)t, p);
            }
        }
    }
    __syncthreads();

    // phase B: wave-cooperative move, 8 rows per wave iteration, 16B per lane
    uint32_t n = sCount;
    int lane = tid & 63;
    int wid  = tid >> 6;                  // 4 waves
    int sub  = lane >> 3;                 // row slot within wave (0..7)
    int fidx = lane & 7;                  // float4 index within row (0..7)
    for (uint32_t r = (uint32_t)(wid * 8 + sub); r < n; r += 32u) {
        uint32_t tt = sT[r], pp = sP[r];
        f32x4 v = __builtin_nontemporal_load((const f32x4*)(tfeat + (size_t)tt * 32) + fidx);
        __builtin_nontemporal_store(v, (f32x4*)(feat + (size_t)pp * 32) + fidx);
    }
}

// ---------------- phase 5: drain overflow (rare duplicate contributors) ----------------
__global__ void drain_ovf(const float* __restrict__ tfeat, const uint2* __restrict__ ovf,
                          const uint32_t* __restrict__ ovfCount, float* __restrict__ feat) {
    uint32_t n = *ovfCount;
    for (uint32_t i = blockIdx.x * blockDim.x + threadIdx.x; i < n;
         i += gridDim.x * blockDim.x) {
        uint2 e = ovf[i];
        const float4* src = (const float4*)(tfeat + (size_t)e.x * 32);
        float* dst = feat + (size_t)e.y * 32;
        #pragma unroll
        for (int q = 0; q < 8; ++q) {
            float4 f = src[q];
            atomicAdd(dst + q * 4 + 0, f.x);
            atomicAdd(dst + q * 4 + 1, f.y);
            atomicAdd(dst + q * 4 + 2, f.z);
            atomicAdd(dst + q * 4 + 3, f.w);
        }
    }
}

extern "C" void kernel_launch(void* const* d_in, const int* in_sizes, int n_in,
                              void* d_out, int out_size, void* d_ws, size_t ws_size,
                              hipStream_t stream) {
    const float* tfeat = (const float*)d_in[0];
    const int*   tidx  = (const int*)d_in[1];
    const int*   sidx  = (const int*)d_in[2];

    const int NT = in_sizes[1] / 4;
    const int NS = in_sizes[2] / 4;

    float* feat = (float*)d_out;                        // [NS, 32]
    float* outI = (float*)d_out + (size_t)NS * 32;      // [NS, 4] as floats

    // workspace: [words 21.5MB][cnt NS*4][ovfCount 4 + pad 4] <- one contiguous zero-fill
    //            [groupSum 656*4][prefixArr 10.7MB][ovf NT*8]    (~50MB << ~1GB ws)
    char* base = (char*)d_ws;
    u64*      words    = (u64*)base;
    uint32_t* cnt      = (uint32_t*)(base + (size_t)NWORDS * 8);
    uint32_t* ovfCount = cnt + NS;
    size_t    zeroBytes = (size_t)NWORDS * 8 + (size_t)NS * 4 + 8;
    uint32_t* groupSum  = ovfCount + 2;
    uint32_t* prefixArr = groupSum + NGROUPS;
    uint2*    ovf       = (uint2*)(prefixArr + NWORDS);

    hipMemsetAsync(d_ws, 0, zeroBytes, stream);

    set_bits<<<(NS + 255) / 256, 256, 0, stream>>>(sidx, words, NS);
    group_popcount<<<NGROUPS, 256, 0, stream>>>(words, groupSum);
    word_prefix_indice<<<NGROUPS, 256, 0, stream>>>(words, groupSum, prefixArr, outI);
    teacher_fused<<<(NT + 255) / 256, 256, 0, stream>>>(tidx, tfeat, words, prefixArr, cnt,
                                                        ovf, ovfCount, feat, NT);
    drain_ovf<<<512, 256, 0, stream>>>(tfeat, ovf, ovfCount, feat);
}

// Round 20
// 198.106 us; speedup vs baseline: 1.0503x; 1.0503x over previous
//
#include <hip/hip_runtime.h>
#include <stdint.h>

typedef unsigned long long u64;

// key: ((b*41+z)<<20) | y<<10 | x   (b<4, z<41, y,x<1024)
// -> 164*2^20 = 171,966,464 keys; monotone-equivalent to reference hash
// b*1025^3+z*1025^2+y*1025+x (lex order (b,z,y,x) preserved, bijective).
#define NWORDS 2686976u             // 164*2^20/64 words
#define GW 4096u                    // words per block (256 thr x 16 words)
#define NGROUPS 656u                // NWORDS/GW (exact)

__device__ __forceinline__ uint32_t pack4(int4 v) {
    // v = (b, z, y, x)
    return (((uint32_t)v.x * 41u + (uint32_t)v.y) << 20) |
           ((uint32_t)v.z << 10) | (uint32_t)v.w;
}

// ---------------- phase 1: presence bits ----------------
// Fire-and-forget atomicOr only (round-6 lesson: no contended counters, no return use).
// words[] is a bare u64 bitmap (21.5 MB) — round-13: split word/prefix arrays halve
// every table pass; the probe's two loads are address-independent anyway.
// (round-19 lesson: nontemporal hints on the single-touch streams REGRESS ~9us —
// they defeat L2 write-coalescing on scattered stores; default caching is optimal.)
__global__ void set_bits(const int* __restrict__ sidx, u64* __restrict__ words, int ns) {
    int i = blockIdx.x * blockDim.x + threadIdx.x;
    if (i >= ns) return;
    uint32_t k = pack4(((const int4*)sidx)[i]);
    atomicOr(&words[k >> 6], 1ull << (k & 63u));
}

// ---------------- phase 2: per-group bit counts (wave-coalesced streaming reads) ----------------
__global__ void group_popcount(const u64* __restrict__ words, uint32_t* __restrict__ groupSum) {
    __shared__ uint32_t s[256];
    uint32_t t = 0;
    size_t base = (size_t)blockIdx.x * GW;
    #pragma unroll
    for (int j = 0; j < 16; ++j)
        t += (uint32_t)__popcll(words[base + j * 256u + threadIdx.x]);
    s[threadIdx.x] = t;
    __syncthreads();
    #pragma unroll
    for (int off = 128; off > 0; off >>= 1) {
        if (threadIdx.x < (unsigned)off) s[threadIdx.x] += s[threadIdx.x + off];
        __syncthreads();
    }
    if (threadIdx.x == 0) groupSum[blockIdx.x] = s[0];
}

// ---------------- phase 3: per-word prefix + sorted decoded indice ----------------
// groupSum entries are FINALIZED by the kernel boundary (round-10 lesson: no
// intra-kernel cross-XCD producer-consumer spin). prefixArr writes are dense
// coalesced lines; words[] is read-only here.
__global__ void word_prefix_indice(const u64* __restrict__ words,
                                   const uint32_t* __restrict__ groupSum,
                                   uint32_t* __restrict__ prefixArr,
                                   float* __restrict__ outI) {
    __shared__ uint32_t s[256];
    __shared__ uint32_t baseSh;
    const int tid = threadIdx.x, bid = blockIdx.x;
    size_t w0 = (size_t)bid * GW + (size_t)tid * 16;
    u64 w[16];
    uint32_t tsum = 0;
    #pragma unroll
    for (int j = 0; j < 16; ++j) { w[j] = words[w0 + j]; tsum += (uint32_t)__popcll(w[j]); }
    s[tid] = tsum;
    __syncthreads();
    #pragma unroll
    for (int off = 1; off < 256; off <<= 1) {
        uint32_t u = (tid >= off) ? s[tid - off] : 0u;
        __syncthreads();
        s[tid] += u;
        __syncthreads();
    }
    uint32_t exclInBlock = s[tid] - tsum;
    // wave 0: sum of preceding blocks' totals (empty loop for bid==0 -> 0)
    if (tid < 64) {
        uint32_t sum = 0;
        for (int g = tid; g < bid; g += 64) sum += groupSum[g];
        #pragma unroll
        for (int off = 32; off > 0; off >>= 1) sum += __shfl_down(sum, off);
        if (tid == 0) baseSh = sum;
    }
    __syncthreads();
    uint32_t run = baseSh + exclInBlock;   // exclusive rank at this thread's first word
    #pragma unroll
    for (int j = 0; j < 16; ++j) {
        prefixArr[w0 + j] = run;
        u64 word = w[j];
        uint32_t kw = (uint32_t)(w0 + j) << 6;
        while (word) {
            int b = (int)__builtin_ctzll(word);
            word &= word - 1;
            uint32_t k = kw | (uint32_t)b;
            uint32_t bz = k >> 20;
            ((float4*)outI)[run++] = make_float4(
                (float)(bz / 41u), (float)(bz % 41u),
                (float)((k >> 10) & 1023u), (float)(k & 1023u));
        }
    }
}

// ---------------- phase 4: fused teacher pass — compact claims, then move cooperatively ----
// Phase A (per-thread): probe (2 independent random loads) + claim atomic; winners
// record (t,p) into an LDS compaction buffer (LDS = trivially coherent; rounds 15-17
// showed cross-kernel scattered 4B winner hand-off loses claims — keep it in-block).
// Losers (~46K of 2M) append to the global overflow list (8B entries; validated
// absmax-0 across rounds 11-14, 18).
// Phase B (per-wave): move claimed rows 8-per-wave-issue — lanes (sub=lane>>3,
// fidx=lane&7) give each row 8 lanes x float4 = 128B, 100% lane-active, fully
// coalesced per row. LDS compaction order is nondeterministic but the SET is
// deterministic and each row is moved exactly once -> deterministic output.
__global__ void teacher_fused(const int* __restrict__ tidx, const float* __restrict__ tfeat,
                              const u64* __restrict__ words, const uint32_t* __restrict__ prefixArr,
                              uint32_t* __restrict__ cnt,
                              uint2* __restrict__ ovf, uint32_t* __restrict__ ovfCount,
                              float* __restrict__ feat, int nt) {
    __shared__ uint32_t sT[256];
    __shared__ uint32_t sP[256];
    __shared__ uint32_t sCount;
    const int tid = threadIdx.x;
    int t = blockIdx.x * 256 + tid;

    if (tid == 0) sCount = 0u;
    __syncthreads();

    if (t < nt) {
        uint32_t k = pack4(((const int4*)tidx)[t]);
        u64 word = words[k >> 6];                 // independent random loads
        uint32_t pfx = prefixArr[k >> 6];
        u64 bit = 1ull << (k & 63u);
        if (word & bit) {
            uint32_t p = pfx + (uint32_t)__popcll(word & (bit - 1ull));
            uint32_t old = atomicAdd(&cnt[p], 1u);
            if (old == 0u) {
                uint32_t i = atomicAdd(&sCount, 1u);   // LDS atomic: cheap
                sT[i] = (uint32_t)t;
                sP[i] = p;
            } else {
                uint32_t idx = atomicAdd(ovfCount, 1u);
                ovf[idx] = make_uint2((uint32_t)t, p);
            }
        }
    }
    __syncthreads();

    // phase B: wave-cooperative move, 8 rows per wave iteration, 16B per lane
    uint32_t n = sCount;
    int lane = tid & 63;
    int wid  = tid >> 6;                  // 4 waves
    int sub  = lane >> 3;                 // row slot within wave (0..7)
    int fidx = lane & 7;                  // float4 index within row (0..7)
    for (uint32_t r = (uint32_t)(wid * 8 + sub); r < n; r += 32u) {
        uint32_t tt = sT[r], pp = sP[r];
        float4 v = ((const float4*)(tfeat + (size_t)tt * 32))[fidx];
        ((float4*)(feat + (size_t)pp * 32))[fidx] = v;
    }
}

// ---------------- phase 5: drain overflow (rare duplicate contributors) ----------------
__global__ void drain_ovf(const float* __restrict__ tfeat, const uint2* __restrict__ ovf,
                          const uint32_t* __restrict__ ovfCount, float* __restrict__ feat) {
    uint32_t n = *ovfCount;
    for (uint32_t i = blockIdx.x * blockDim.x + threadIdx.x; i < n;
         i += gridDim.x * blockDim.x) {
        uint2 e = ovf[i];
        const float4* src = (const float4*)(tfeat + (size_t)e.x * 32);
        float* dst = feat + (size_t)e.y * 32;
        #pragma unroll
        for (int q = 0; q < 8; ++q) {
            float4 f = src[q];
            atomicAdd(dst + q * 4 + 0, f.x);
            atomicAdd(dst + q * 4 + 1, f.y);
            atomicAdd(dst + q * 4 + 2, f.z);
            atomicAdd(dst + q * 4 + 3, f.w);
        }
    }
}

extern "C" void kernel_launch(void* const* d_in, const int* in_sizes, int n_in,
                              void* d_out, int out_size, void* d_ws, size_t ws_size,
                              hipStream_t stream) {
    const float* tfeat = (const float*)d_in[0];
    const int*   tidx  = (const int*)d_in[1];
    const int*   sidx  = (const int*)d_in[2];

    const int NT = in_sizes[1] / 4;
    const int NS = in_sizes[2] / 4;

    float* feat = (float*)d_out;                        // [NS, 32]
    float* outI = (float*)d_out + (size_t)NS * 32;      // [NS, 4] as floats

    // workspace: [words 21.5MB][cnt NS*4][ovfCount 4 + pad 4] <- one contiguous zero-fill
    //            [groupSum 656*4][prefixArr 10.7MB][ovf NT*8]    (~50MB << ~1GB ws)
    char* base = (char*)d_ws;
    u64*      words    = (u64*)base;
    uint32_t* cnt      = (uint32_t*)(base + (size_t)NWORDS * 8);
    uint32_t* ovfCount = cnt + NS;
    size_t    zeroBytes = (size_t)NWORDS * 8 + (size_t)NS * 4 + 8;
    uint32_t* groupSum  = ovfCount + 2;
    uint32_t* prefixArr = groupSum + NGROUPS;
    uint2*    ovf       = (uint2*)(prefixArr + NWORDS);

    hipMemsetAsync(d_ws, 0, zeroBytes, stream);

    set_bits<<<(NS + 255) / 256, 256, 0, stream>>>(sidx, words, NS);
    group_popcount<<<NGROUPS, 256, 0, stream>>>(words, groupSum);
    word_prefix_indice<<<NGROUPS, 256, 0, stream>>>(words, groupSum, prefixArr, outI);
    teacher_fused<<<(NT + 255) / 256, 256, 0, stream>>>(tidx, tfeat, words, prefixArr, cnt,
                                                        ovf, ovfCount, feat, NT);
    drain_ovf<<<512, 256, 0, stream>>>(tfeat, ovf, ovfCount, feat);
}